// Round 1
// baseline (120.108 us; speedup 1.0000x reference)
//
#include <hip/hip_runtime.h>
#include <hip/hip_bf16.h>
#include <stdint.h>

// Problem constants
#define BB   32
#define CIN  128
#define HH   64
#define WW   64
#define COUT 256
#define OHH  62
#define OWW  62
#define PIX_PER_B (OHH*OWW)        // 3844
#define NPIX (BB*PIX_PER_B)        // 123008 = 961 * 128
#define KTOT (9*CIN)               // 1152

typedef __bf16 bf16x8 __attribute__((ext_vector_type(8)));
typedef float  f32x4  __attribute__((ext_vector_type(4)));
typedef uint16_t u16x8 __attribute__((ext_vector_type(8)));

__device__ __forceinline__ uint16_t f2bf(float f) {
    uint32_t u = __float_as_uint(f);
    uint32_t r = (u + 0x7FFFu + ((u >> 16) & 1u)) >> 16;
    return (uint16_t)r;
}

__device__ __forceinline__ void gload_lds16(const void* g, void* l) {
    __builtin_amdgcn_global_load_lds(
        (const __attribute__((address_space(1))) uint32_t*)g,
        (__attribute__((address_space(3))) uint32_t*)l, 16, 0, 0);
}

// -------- Prepass 1: NCHW fp32 -> NHWC bf16 ----------------------------------
// grid: 32*64 slabs (b,h); 256 threads. Reads coalesced along w per channel,
// writes 16B/lane at 256B stride (L2 merges; full rows covered within block).
__global__ void __launch_bounds__(256) to_nhwc(const float* __restrict__ in,
                                               uint16_t* __restrict__ out) {
    int slab = blockIdx.x;            // b*64 + h
    int b = slab >> 6, h = slab & 63;
    int w  = threadIdx.x & 63;
    int cp = threadIdx.x >> 6;        // 0..3
    const float* src = in + (((size_t)b * CIN) * HH + h) * WW + w;
    uint16_t* dst = out + ((size_t)slab * WW + w) * CIN;
    #pragma unroll
    for (int it = 0; it < 4; ++it) {
        int c0 = cp * 32 + it * 8;
        u16x8 v;
        #pragma unroll
        for (int j = 0; j < 8; ++j) v[j] = f2bf(src[(c0 + j) * (HH * WW)]);
        *reinterpret_cast<u16x8*>(dst + c0) = v;
    }
}

// -------- Prepass 2: OIHW fp32 -> bf16 [o][uv*128 + c] -----------------------
__global__ void __launch_bounds__(256) pack_w(const float* __restrict__ w,
                                              uint16_t* __restrict__ out) {
    int idx = blockIdx.x * 256 + threadIdx.x;     // < 256*1152
    int o = idx / KTOT;
    int k = idx - o * KTOT;
    int uv = k >> 7, c = k & 127;
    out[idx] = f2bf(w[(o * CIN + c) * 9 + uv]);
}

// -------- Main MFMA implicit-GEMM kernel -------------------------------------
// Tile: BM=128 (c_out) x BN=128 (pixels), BK=64. 4 waves, each 64x64 out.
// A = weights [o][k] (row-major, k contig). B = X [pixel][k] via NHWC (k=c contig
// for fixed (u,v)). Both staged to LDS via global_load_lds w/ pre-swizzled src.
__global__ void __launch_bounds__(256) conv_mfma(
        const uint16_t* __restrict__ Xg,   // NHWC bf16 [32][64][64][128]
        const uint16_t* __restrict__ Wg,   // bf16 [256][1152], k=(uv,c)
        const float*    __restrict__ bias, // [256]
        float*          __restrict__ out)  // NCHW fp32 [32][256][62][62]
{
    __shared__ char lds[32 * 1024 + 1024];
    char* Alds = lds;                 // 16 KiB: [128 o-rows][64 k] bf16, swizzled
    char* Xlds = lds + 16 * 1024;     // 16 KiB: [128 pix ][64 k] bf16, swizzled
    int*  pbase = (int*)(lds + 32 * 1024);        // 128: NHWC elem offset of pixel
    int*  obase = (int*)(lds + 32 * 1024 + 512);  // 128: out flat base (o=0)

    const int tid  = threadIdx.x;
    const int lane = tid & 63;
    const int wid  = tid >> 6;
    const int bid  = blockIdx.x;
    const int mt = bid & 1;           // c_out tile (0..1)
    const int nt = bid >> 1;          // pixel tile (0..960)

    if (tid < 128) {
        int n  = nt * 128 + tid;
        int b  = n / PIX_PER_B;
        int rem = n - b * PIX_PER_B;
        int oh = rem / OWW;
        int ow = rem - oh * OWW;
        pbase[tid] = ((b * 64 + oh) * 64 + ow) * 128;
        obase[tid] = b * (COUT * PIX_PER_B) + rem;
    }
    __syncthreads();

    // Staging geometry: per tile, 16 wave-instrs of 1KiB (64 lanes x 16B).
    // instr t covers rows [t*8, t*8+8), lane covers row t*8+(lane>>3), chunk lane&7.
    // Swizzle: stored chunk (lane&7) holds logical chunk (lane&7)^(row&7).
    const int kc = ((lane & 7) ^ ((lane >> 3) & 7)) * 16;  // src byte offset of chunk
    int xrow_off[4];  // NHWC elem base per q (pixel of this lane's staging row)
    int arow_off[4];  // Wg elem base per q
    #pragma unroll
    for (int q = 0; q < 4; ++q) {
        int t   = wid * 4 + q;
        int row = t * 8 + (lane >> 3);
        xrow_off[q] = pbase[row];
        arow_off[q] = (mt * 128 + row) * KTOT;
    }

    f32x4 acc[4][4] = {};
    const char* XgB = (const char*)Xg;
    const char* WgB = (const char*)Wg;
    const int wm = wid >> 1, wn = wid & 1;

    for (int uv = 0; uv < 9; ++uv) {
        int u = uv / 3, v = uv - u * 3;
        int ioff = (u * 64 + v) * 128;           // NHWC elem offset for (u,v)
        #pragma unroll
        for (int ch = 0; ch < 2; ++ch) {
            int c0   = ch * 64;
            int koff = uv * 128 + c0;            // k base in Wg
            // ---- stage A (weights) and B (pixels) tiles ----
            #pragma unroll
            for (int q = 0; q < 4; ++q) {
                int t = wid * 4 + q;
                gload_lds16(WgB + 2 * (arow_off[q] + koff) + kc,
                            Alds + t * 1024 + lane * 16);
                gload_lds16(XgB + 2 * (xrow_off[q] + ioff + c0) + kc,
                            Xlds + t * 1024 + lane * 16);
            }
            __syncthreads();
            // ---- compute ----
            #pragma unroll
            for (int ks = 0; ks < 2; ++ks) {
                bf16x8 af[4], xf[4];
                #pragma unroll
                for (int mi = 0; mi < 4; ++mi) {
                    int row = wm * 64 + mi * 16 + (lane & 15);
                    int by  = row * 128 +
                              ((ks * 64 + (lane >> 4) * 16) ^ ((row & 7) << 4));
                    af[mi] = *reinterpret_cast<const bf16x8*>(Alds + by);
                }
                #pragma unroll
                for (int nj = 0; nj < 4; ++nj) {
                    int row = wn * 64 + nj * 16 + (lane & 15);
                    int by  = row * 128 +
                              ((ks * 64 + (lane >> 4) * 16) ^ ((row & 7) << 4));
                    xf[nj] = *reinterpret_cast<const bf16x8*>(Xlds + by);
                }
                #pragma unroll
                for (int mi = 0; mi < 4; ++mi)
                    #pragma unroll
                    for (int nj = 0; nj < 4; ++nj)
                        acc[mi][nj] = __builtin_amdgcn_mfma_f32_16x16x32_bf16(
                            af[mi], xf[nj], acc[mi][nj], 0, 0, 0);
            }
            __syncthreads();
        }
    }

    // ---- epilogue: C/D layout col=lane&15 (pixel), row=(lane>>4)*4+reg (o) ----
    #pragma unroll
    for (int mi = 0; mi < 4; ++mi) {
        int o = mt * 128 + wm * 64 + mi * 16 + (lane >> 4) * 4;
        #pragma unroll
        for (int reg = 0; reg < 4; ++reg) {
            float bv = bias[o + reg];
            #pragma unroll
            for (int nj = 0; nj < 4; ++nj) {
                int pl  = wn * 64 + nj * 16 + (lane & 15);
                int off = obase[pl] + (o + reg) * PIX_PER_B;
                out[off] = acc[mi][nj][reg] + bv;
            }
        }
    }
}

// -------- Fallback (ws too small): naive direct conv -------------------------
__global__ void __launch_bounds__(256) conv_naive(const float* __restrict__ in,
                                                  const float* __restrict__ w,
                                                  const float* __restrict__ bias,
                                                  float* __restrict__ out) {
    long idx = (long)blockIdx.x * 256 + threadIdx.x;
    int t = (int)idx;
    int ow = t % OWW; t /= OWW;
    int oh = t % OHH; t /= OHH;
    int o  = t % COUT;
    int b  = t / COUT;
    float s = bias[o];
    for (int c = 0; c < CIN; ++c)
        for (int u = 0; u < 3; ++u)
            for (int v = 0; v < 3; ++v)
                s += in[((b * CIN + c) * HH + oh + u) * WW + ow + v] *
                     w[((o * CIN + c) * 3 + u) * 3 + v];
    out[idx] = s;
}

extern "C" void kernel_launch(void* const* d_in, const int* in_sizes, int n_in,
                              void* d_out, int out_size, void* d_ws, size_t ws_size,
                              hipStream_t stream) {
    const float* in   = (const float*)d_in[0];
    const float* wt   = (const float*)d_in[1];
    const float* bias = (const float*)d_in[2];
    float* out = (float*)d_out;

    const size_t xg_elems = (size_t)BB * HH * WW * CIN;       // 33.5M bf16
    const size_t wg_elems = (size_t)COUT * KTOT;              // 295K bf16
    const size_t need = (xg_elems + wg_elems) * sizeof(uint16_t);

    if (ws_size < need) {
        long total = (long)BB * COUT * OHH * OWW;
        conv_naive<<<(int)((total + 255) / 256), 256, 0, stream>>>(in, wt, bias, out);
        return;
    }

    uint16_t* Xg = (uint16_t*)d_ws;
    uint16_t* Wg = Xg + xg_elems;

    to_nhwc<<<BB * HH, 256, 0, stream>>>(in, Xg);
    pack_w<<<(COUT * KTOT) / 256, 256, 0, stream>>>(wt, Wg);
    conv_mfma<<<2 * (NPIX / 128), 256, 0, stream>>>(Xg, Wg, bias, out);
}

// Round 2
// 116.968 us; speedup vs baseline: 1.0268x; 1.0268x over previous
//
#include <hip/hip_runtime.h>
#include <hip/hip_bf16.h>
#include <stdint.h>

// Problem constants
#define BB   32
#define CIN  128
#define HH   64
#define WW   64
#define COUT 256
#define OHH  62
#define OWW  62
#define PIX_PER_B (OHH*OWW)        // 3844
#define NPIX (BB*PIX_PER_B)        // 123008 = 961 * 128
#define KTOT (9*CIN)               // 1152
#define NKT  18                    // K-tiles of BK=64
#define SLOT_BYTES 49152           // A 32KB + X 16KB per K-tile

typedef __bf16 bf16x8 __attribute__((ext_vector_type(8)));
typedef float  f32x4  __attribute__((ext_vector_type(4)));
typedef uint16_t u16x8 __attribute__((ext_vector_type(8)));

__device__ __forceinline__ uint16_t f2bf(float f) {
    uint32_t u = __float_as_uint(f);
    uint32_t r = (u + 0x7FFFu + ((u >> 16) & 1u)) >> 16;
    return (uint16_t)r;
}

__device__ __forceinline__ void gload_lds16(const void* g, void* l) {
    __builtin_amdgcn_global_load_lds(
        (const __attribute__((address_space(1))) uint32_t*)g,
        (__attribute__((address_space(3))) uint32_t*)l, 16, 0, 0);
}

// -------- Prepass 1: NCHW fp32 -> NHWC bf16 ----------------------------------
__global__ void __launch_bounds__(256) to_nhwc(const float* __restrict__ in,
                                               uint16_t* __restrict__ out) {
    int slab = blockIdx.x;            // b*64 + h
    int b = slab >> 6, h = slab & 63;
    int w  = threadIdx.x & 63;
    int cp = threadIdx.x >> 6;        // 0..3
    const float* src = in + (((size_t)b * CIN) * HH + h) * WW + w;
    uint16_t* dst = out + ((size_t)slab * WW + w) * CIN;
    #pragma unroll
    for (int it = 0; it < 4; ++it) {
        int c0 = cp * 32 + it * 8;
        u16x8 v;
        #pragma unroll
        for (int j = 0; j < 8; ++j) v[j] = f2bf(src[(c0 + j) * (HH * WW)]);
        *reinterpret_cast<u16x8*>(dst + c0) = v;
    }
}

// -------- Prepass 2: OIHW fp32 -> bf16 [o][uv*128 + c] -----------------------
__global__ void __launch_bounds__(256) pack_w(const float* __restrict__ w,
                                              uint16_t* __restrict__ out) {
    int idx = blockIdx.x * 256 + threadIdx.x;     // < 256*1152
    int o = idx / KTOT;
    int k = idx - o * KTOT;
    int uv = k >> 7, c = k & 127;
    out[idx] = f2bf(w[(o * CIN + c) * 9 + uv]);
}

// -------- Main: 256x128 tile, 8 waves, ring-3 LDS, counted vmcnt -------------
// A = weights [256][1152] bf16 (k contig). X = pixels [128][k] via NHWC.
// Per K-tile (BK=64): A-tile 256x64 (32KB, 4 stage loads), X-tile 128x64
// (16KB, 2 stage loads). 3 LDS slots; while computing K-tile k, stage k+2
// into slot freed by k-1. vmcnt(6) once per K-tile (one K-tile in flight).
__global__ void __launch_bounds__(512, 2) conv_mfma8(
        const uint16_t* __restrict__ Xg,   // NHWC bf16 [32][64][64][128]
        const uint16_t* __restrict__ Wg,   // bf16 [256][1152], k=(uv,c)
        const float*    __restrict__ bias, // [256]
        float*          __restrict__ out)  // NCHW fp32 [32][256][62][62]
{
    __shared__ char lds[3 * SLOT_BYTES + 1024];
    int* pbase = (int*)(lds + 3 * SLOT_BYTES);   // [128] NHWC elem off of pixel
    int* obase = pbase + 128;                    // [128] out flat base (o=0)

    const int tid  = threadIdx.x;
    const int lane = tid & 63;
    const int wid  = tid >> 6;          // 0..7

    // bijective XCD swizzle (m204): nwg=961, q=120, r=1
    int bid = blockIdx.x;
    int xcd = bid & 7, lid = bid >> 3;
    int nt  = (xcd == 0 ? 0 : 121 + (xcd - 1) * 120) + lid;

    if (tid < 128) {
        int n   = nt * 128 + tid;
        int b   = n / PIX_PER_B;
        int rem = n - b * PIX_PER_B;
        int oh  = rem / OWW;
        int ow  = rem - oh * OWW;
        pbase[tid] = ((b * 64 + oh) * 64 + ow) * 128;
        obase[tid] = b * (COUT * PIX_PER_B) + rem;
    }
    __syncthreads();

    // ---- staging geometry: load-index j covers rows j*64+(tid>>3), chunk tid&7
    const int row8 = tid >> 3;                       // 0..63
    const int ch   = tid & 7;
    const int kc   = ((ch ^ (row8 & 7)) << 4);       // pre-swizzled src byte off
    const char* WgB = (const char*)Wg;
    const char* XgB = (const char*)Xg;
    int aoff[4], xoff[2];
    #pragma unroll
    for (int j = 0; j < 4; ++j) aoff[j] = (j * 64 + row8) * (KTOT * 2);
    #pragma unroll
    for (int j = 0; j < 2; ++j) xoff[j] = pbase[j * 64 + row8] * 2;
    const int ldst = tid * 16;

    auto stage_half = [&](int k, char* sbase, int h) {
        int uvv = k >> 1;
        int u   = uvv / 3, v = uvv - u * 3;
        int c0b = (k & 1) * 128;                       // bytes (64 elems)
        int wk  = uvv * 256 + c0b;                     // Wg k-byte offset
        int xk  = (u * 64 + v) * 256 + c0b;            // NHWC (u,v) byte offset
        char* A = sbase;
        char* X = sbase + 32768;
        if (h == 0) {
            gload_lds16(WgB + (aoff[0] + wk + kc), A + 0 * 8192 + ldst);
            gload_lds16(WgB + (aoff[1] + wk + kc), A + 1 * 8192 + ldst);
            gload_lds16(XgB + (xoff[0] + xk + kc), X + 0 * 8192 + ldst);
        } else {
            gload_lds16(WgB + (aoff[2] + wk + kc), A + 2 * 8192 + ldst);
            gload_lds16(WgB + (aoff[3] + wk + kc), A + 3 * 8192 + ldst);
            gload_lds16(XgB + (xoff[1] + xk + kc), X + 1 * 8192 + ldst);
        }
    };

    // ---- fragment ds_read byte offsets (loop-invariant) ----
    const int wm = wid >> 1, wn = wid & 1;   // 4 M-waves x 2 N-waves
    int aro[4][2], xro[4][2];
    #pragma unroll
    for (int mi = 0; mi < 4; ++mi) {
        int row = wm * 64 + mi * 16 + (lane & 15);
        #pragma unroll
        for (int ks = 0; ks < 2; ++ks)
            aro[mi][ks] = row * 128 +
                ((ks * 64 + (lane >> 4) * 16) ^ ((row & 7) << 4));
    }
    #pragma unroll
    for (int nj = 0; nj < 4; ++nj) {
        int row = wn * 64 + nj * 16 + (lane & 15);
        #pragma unroll
        for (int ks = 0; ks < 2; ++ks)
            xro[nj][ks] = 32768 + row * 128 +
                ((ks * 64 + (lane >> 4) * 16) ^ ((row & 7) << 4));
    }

    f32x4 acc[4][4] = {};

    // ---- prologue: stage K-tiles 0 and 1 ----
    stage_half(0, lds + 0 * SLOT_BYTES, 0);
    stage_half(0, lds + 0 * SLOT_BYTES, 1);
    stage_half(1, lds + 1 * SLOT_BYTES, 0);
    stage_half(1, lds + 1 * SLOT_BYTES, 1);
    asm volatile("s_waitcnt vmcnt(6)" ::: "memory");   // K-tile 0 resident
    __builtin_amdgcn_s_barrier();

    int s = 0, s2 = 2;
    for (int kt = 0; kt < NKT; ++kt) {
        char* sb  = lds + s  * SLOT_BYTES;
        char* sb2 = lds + s2 * SLOT_BYTES;
        #pragma unroll
        for (int ks = 0; ks < 2; ++ks) {
            bf16x8 af[4], xf[4];
            #pragma unroll
            for (int mi = 0; mi < 4; ++mi)
                af[mi] = *reinterpret_cast<const bf16x8*>(sb + aro[mi][ks]);
            #pragma unroll
            for (int nj = 0; nj < 4; ++nj)
                xf[nj] = *reinterpret_cast<const bf16x8*>(sb + xro[nj][ks]);
            if (kt < NKT - 2) stage_half(kt + 2, sb2, ks);
            __builtin_amdgcn_s_barrier();
            __builtin_amdgcn_s_setprio(1);
            #pragma unroll
            for (int mi = 0; mi < 4; ++mi)
                #pragma unroll
                for (int nj = 0; nj < 4; ++nj)
                    acc[mi][nj] = __builtin_amdgcn_mfma_f32_16x16x32_bf16(
                        af[mi], xf[nj], acc[mi][nj], 0, 0, 0);
            __builtin_amdgcn_s_setprio(0);
            if (ks == 0) {
                __builtin_amdgcn_s_barrier();
            } else {
                // quad end: wait for next K-tile's 6 loads (oldest), keep
                // the just-issued 6 (kt+2) in flight. Tail: full drain once.
                if (kt < NKT - 2)
                    asm volatile("s_waitcnt vmcnt(6)" ::: "memory");
                else if (kt == NKT - 2)
                    asm volatile("s_waitcnt vmcnt(0)" ::: "memory");
                __builtin_amdgcn_s_barrier();
            }
        }
        s  = (s  == 2) ? 0 : s  + 1;
        s2 = (s2 == 2) ? 0 : s2 + 1;
    }

    // ---- epilogue: C/D col=lane&15 (pixel), row=(lane>>4)*4+reg (o) ----
    #pragma unroll
    for (int mi = 0; mi < 4; ++mi) {
        int o = wm * 64 + mi * 16 + ((lane >> 4) << 2);
        #pragma unroll
        for (int reg = 0; reg < 4; ++reg) {
            float bv = bias[o + reg];
            #pragma unroll
            for (int nj = 0; nj < 4; ++nj) {
                int pl = wn * 64 + nj * 16 + (lane & 15);
                out[obase[pl] + (o + reg) * PIX_PER_B] = acc[mi][nj][reg] + bv;
            }
        }
    }
}

// -------- Fallback (ws too small): naive direct conv -------------------------
__global__ void __launch_bounds__(256) conv_naive(const float* __restrict__ in,
                                                  const float* __restrict__ w,
                                                  const float* __restrict__ bias,
                                                  float* __restrict__ out) {
    long idx = (long)blockIdx.x * 256 + threadIdx.x;
    int t = (int)idx;
    int ow = t % OWW; t /= OWW;
    int oh = t % OHH; t /= OHH;
    int o  = t % COUT;
    int b  = t / COUT;
    float s = bias[o];
    for (int c = 0; c < CIN; ++c)
        for (int u = 0; u < 3; ++u)
            for (int v = 0; v < 3; ++v)
                s += in[((b * CIN + c) * HH + oh + u) * WW + ow + v] *
                     w[((o * CIN + c) * 3 + u) * 3 + v];
    out[idx] = s;
}

extern "C" void kernel_launch(void* const* d_in, const int* in_sizes, int n_in,
                              void* d_out, int out_size, void* d_ws, size_t ws_size,
                              hipStream_t stream) {
    const float* in   = (const float*)d_in[0];
    const float* wt   = (const float*)d_in[1];
    const float* bias = (const float*)d_in[2];
    float* out = (float*)d_out;

    const size_t xg_elems = (size_t)BB * HH * WW * CIN;       // 33.5M bf16
    const size_t wg_elems = (size_t)COUT * KTOT;              // 295K bf16
    const size_t need = (xg_elems + wg_elems) * sizeof(uint16_t);

    if (ws_size < need) {
        long total = (long)BB * COUT * OHH * OWW;
        conv_naive<<<(int)((total + 255) / 256), 256, 0, stream>>>(in, wt, bias, out);
        return;
    }

    uint16_t* Xg = (uint16_t*)d_ws;
    uint16_t* Wg = Xg + xg_elems;

    to_nhwc<<<BB * HH, 256, 0, stream>>>(in, Xg);
    pack_w<<<(COUT * KTOT) / 256, 256, 0, stream>>>(wt, Wg);
    conv_mfma8<<<NPIX / 128, 512, 0, stream>>>(Xg, Wg, bias, out);
}